// Round 1
// baseline (70.150 us; speedup 1.0000x reference)
//
#include <hip/hip_runtime.h>
#include <hip/hip_bf16.h>

#define ACTIONS 64
#define EMB 32
#define DELTA 16
#define EPS 1e-5f

// ---------------- Kernel 1: per-column partial sums ----------------
// x is [n][64] row-major. Grid-stride with stride a multiple of 64 so each
// thread's column is fixed at (tid & 63). Writes [gridDim.x][128] partials
// (64 sums, then 64 sum-of-squares) into workspace. No float atomics ->
// deterministic.
__global__ void __launch_bounds__(256) bn_stats_kernel(const float* __restrict__ x,
                                                       float* __restrict__ partial,
                                                       int total /* n*64 */) {
    const int tid = threadIdx.x;
    float s = 0.0f, sq = 0.0f;
    const int stride = gridDim.x * 256;
    for (int i = blockIdx.x * 256 + tid; i < total; i += stride) {
        float v = x[i];
        s += v;
        sq += v * v;
    }
    __shared__ float ssum[256];
    __shared__ float ssq[256];
    ssum[tid] = s;
    ssq[tid] = sq;
    __syncthreads();
    if (tid < 64) {
        float a = ssum[tid] + ssum[tid + 64] + ssum[tid + 128] + ssum[tid + 192];
        float b = ssq[tid] + ssq[tid + 64] + ssq[tid + 128] + ssq[tid + 192];
        partial[blockIdx.x * 128 + tid]      = a;
        partial[blockIdx.x * 128 + 64 + tid] = b;
    }
}

// ---------------- Kernel 2: fold partials -> scale/shift ----------------
__global__ void __launch_bounds__(64) bn_finalize_kernel(const float* __restrict__ partial,
                                                         const float* __restrict__ w,
                                                         const float* __restrict__ b,
                                                         float* __restrict__ scaleshift,
                                                         int nblocks, float inv_n) {
    const int c = threadIdx.x;  // 0..63
    float s = 0.0f, sq = 0.0f;
    for (int i = 0; i < nblocks; ++i) {
        s  += partial[i * 128 + c];
        sq += partial[i * 128 + 64 + c];
    }
    float mean = s * inv_n;
    float var  = fmaxf(sq * inv_n - mean * mean, 0.0f);
    float scale = rsqrtf(var + EPS) * w[c];
    scaleshift[c]      = scale;
    scaleshift[64 + c] = b[c] - mean * scale;
}

// ---------------- Kernel 3: main spline-embedding ----------------
// One (row,col) "pair" per 8 lanes; each lane handles 4 of the 32 emb floats
// via float4. A wave (64 lanes) covers 8 consecutive pairs -> each float4
// store instruction writes a contiguous 1 KiB segment.
__global__ void __launch_bounds__(256) spline_main_kernel(const float* __restrict__ x,
                                                          const float* __restrict__ emb,
                                                          const float* __restrict__ scaleshift,
                                                          float* __restrict__ out) {
    const int gtid = blockIdx.x * 256 + threadIdx.x;
    const int pair = gtid >> 3;          // (row*64 + col)
    const int sub  = gtid & 7;           // which float4 of the 32-float emb row
    const int col  = pair & 63;

    float xv    = x[pair];
    float scale = scaleshift[col];
    float shift = scaleshift[64 + col];

    float xn = fmaf(xv, scale, shift);
    float t  = tanhf(xn);
    t = fminf(fmaxf(t, -1.0f + 1e-5f), 1.0f - 1e-5f);

    // Mirror reference exactly: xl = floor(t*D); xh = floor(t*D + 1)
    float td = t * (float)DELTA;
    float xlf = floorf(td);
    float xhf = floorf(td + 1.0f);
    int li = ((int)xlf + DELTA) * ACTIONS + col;
    int hi = ((int)xhf + DELTA) * ACTIONS + col;

    // weights: wh = D*(t - xl/D) , wl = D*(xh/D - t)
    float wh = (float)DELTA * (t - xlf * (1.0f / (float)DELTA));
    float wl = (float)DELTA * (xhf * (1.0f / (float)DELTA) - t);

    const float4 bl = *reinterpret_cast<const float4*>(emb + li * EMB + sub * 4);
    const float4 bh = *reinterpret_cast<const float4*>(emb + hi * EMB + sub * 4);

    float4 o;
    o.x = bh.x * wh + bl.x * wl;
    o.y = bh.y * wh + bl.y * wl;
    o.z = bh.z * wh + bl.z * wl;
    o.w = bh.w * wh + bl.w * wl;
    *reinterpret_cast<float4*>(out + (long long)pair * EMB + sub * 4) = o;
}

extern "C" void kernel_launch(void* const* d_in, const int* in_sizes, int n_in,
                              void* d_out, int out_size, void* d_ws, size_t ws_size,
                              hipStream_t stream) {
    const float* x    = (const float*)d_in[0];
    const float* bn_w = (const float*)d_in[1];
    const float* bn_b = (const float*)d_in[2];
    const float* emb  = (const float*)d_in[3];
    float* out        = (float*)d_out;

    const int n = in_sizes[0] / ACTIONS;   // 16384
    const int total = n * ACTIONS;         // 1,048,576

    float* partial    = (float*)d_ws;                 // 128 * 128 floats
    float* scaleshift = (float*)d_ws + 128 * 128;     // 128 floats

    const int STATS_BLOCKS = 128;
    bn_stats_kernel<<<STATS_BLOCKS, 256, 0, stream>>>(x, partial, total);
    bn_finalize_kernel<<<1, 64, 0, stream>>>(partial, bn_w, bn_b, scaleshift,
                                             STATS_BLOCKS, 1.0f / (float)n);

    // 8 lanes per pair -> total*8 threads
    const int threads = 256;
    const int blocks = (total * 8 + threads - 1) / threads;   // 32768
    spline_main_kernel<<<blocks, threads, 0, stream>>>(x, emb, scaleshift, out);
}

// Round 3
// 63.912 us; speedup vs baseline: 1.0976x; 1.0976x over previous
//
#include <hip/hip_runtime.h>
#include <hip/hip_bf16.h>

#define ACTIONS 64
#define EMB 32
#define DELTA 16
#define EPS 1e-5f

typedef float f32x4 __attribute__((ext_vector_type(4)));

// tanh(x) = 1 - 2/(1+exp(2x)); saturates correctly at +-1.
__device__ __forceinline__ float fast_tanhf(float x) {
    float e = __expf(2.0f * x);
    float r = __builtin_amdgcn_rcpf(1.0f + e);
    return 1.0f - 2.0f * r;
}

// ---------------- Kernel 1: per-column partial sums (float4) ----------------
// x is [n][64] row-major. float4 grid-stride; stride is a multiple of 16 vec4s
// so each thread's 4-column group (4*(tid&15)..+3) is fixed. Deterministic.
__global__ void __launch_bounds__(256) bn_stats_kernel(const f32x4* __restrict__ x4,
                                                       float* __restrict__ partial,
                                                       int total4 /* n*64/4 */) {
    const int tid = threadIdx.x;
    f32x4 s = {0.f, 0.f, 0.f, 0.f};
    f32x4 q = {0.f, 0.f, 0.f, 0.f};
    const int stride = gridDim.x * 256;
    for (int i = blockIdx.x * 256 + tid; i < total4; i += stride) {
        f32x4 v = x4[i];
        s += v;
        q += v * v;
    }
    __shared__ f32x4 ssum[256];
    __shared__ f32x4 ssq[256];
    ssum[tid] = s;
    ssq[tid] = q;
    __syncthreads();
    if (tid < 16) {
        f32x4 a = ssum[tid];
        f32x4 b = ssq[tid];
        #pragma unroll
        for (int k = 1; k < 16; ++k) {
            a += ssum[tid + 16 * k];
            b += ssq[tid + 16 * k];
        }
        // columns 4*tid .. 4*tid+3
        float* ps = partial + blockIdx.x * 128;
        #pragma unroll
        for (int j = 0; j < 4; ++j) {
            ps[4 * tid + j]      = a[j];
            ps[64 + 4 * tid + j] = b[j];
        }
    }
}

// ---------------- Kernel 2: fold partials -> scale/shift ----------------
__global__ void __launch_bounds__(64) bn_finalize_kernel(const float* __restrict__ partial,
                                                         const float* __restrict__ w,
                                                         const float* __restrict__ b,
                                                         float* __restrict__ scaleshift,
                                                         int nblocks, float inv_n) {
    const int c = threadIdx.x;  // 0..63
    float s = 0.0f, sq = 0.0f;
    for (int i = 0; i < nblocks; ++i) {
        s  += partial[i * 128 + c];
        sq += partial[i * 128 + 64 + c];
    }
    float mean = s * inv_n;
    float var  = fmaxf(sq * inv_n - mean * mean, 0.0f);
    float scale = rsqrtf(var + EPS) * w[c];
    scaleshift[c]      = scale;
    scaleshift[64 + c] = b[c] - mean * scale;
}

// ---------------- Kernel 3: main spline-embedding ----------------
// Phase 1: each of 256 threads computes ONE pair's params {liByteOff,
// hiByteOff, wl, wh} into LDS (tanh computed once per pair, not 8x).
// Phase 2: 8 iterations; iteration k writes 256 contiguous float4 units
// (4 KiB per block-iteration). LDS param read is broadcast within each
// 8-lane group; 8 distinct float4 addrs/wave span all 32 banks -> no conflict.
__global__ void __launch_bounds__(256) spline_main_kernel(const float* __restrict__ x,
                                                          const float* __restrict__ emb,
                                                          const float* __restrict__ scaleshift,
                                                          float* __restrict__ out) {
    __shared__ f32x4 params[256];
    const int tid = threadIdx.x;
    const int P0  = blockIdx.x * 256;   // first pair of this block

    {
        const int col = tid & 63;       // (P0+tid)&63 == tid&63 since P0%256==0
        float xv    = x[P0 + tid];
        float scale = scaleshift[col];
        float shift = scaleshift[64 + col];

        float t = fast_tanhf(fmaf(xv, scale, shift));
        t = fminf(fmaxf(t, -1.0f + 1e-5f), 1.0f - 1e-5f);

        float td  = t * (float)DELTA;
        float xlf = floorf(td);
        float xhf = floorf(td + 1.0f);   // mirror reference exactly
        int li = ((int)xlf + DELTA) * ACTIONS + col;
        int hi = ((int)xhf + DELTA) * ACTIONS + col;

        f32x4 p;
        p.x = __int_as_float(li * (EMB * 4));
        p.y = __int_as_float(hi * (EMB * 4));
        p.z = xhf - td;    // wl = D*(xh - t)
        p.w = td - xlf;    // wh = D*(t - xl)
        params[tid] = p;
    }
    __syncthreads();

    const char* embB = (const char*)emb;
    f32x4* outv = reinterpret_cast<f32x4*>(out) + (long long)P0 * 8;

    #pragma unroll
    for (int k = 0; k < 8; ++k) {
        const int u = k * 256 + tid;
        f32x4 p = params[u >> 3];
        const int sub = (u & 7) * 16;   // byte offset of this float4 in the row
        const f32x4 bl = *reinterpret_cast<const f32x4*>(embB + __float_as_int(p.x) + sub);
        const f32x4 bh = *reinterpret_cast<const f32x4*>(embB + __float_as_int(p.y) + sub);
        const float wl = p.z, wh = p.w;
        f32x4 o = bh * wh + bl * wl;
        __builtin_nontemporal_store(o, &outv[u]);   // output never re-read
    }
}

extern "C" void kernel_launch(void* const* d_in, const int* in_sizes, int n_in,
                              void* d_out, int out_size, void* d_ws, size_t ws_size,
                              hipStream_t stream) {
    const float* x    = (const float*)d_in[0];
    const float* bn_w = (const float*)d_in[1];
    const float* bn_b = (const float*)d_in[2];
    const float* emb  = (const float*)d_in[3];
    float* out        = (float*)d_out;

    const int n = in_sizes[0] / ACTIONS;   // 16384
    const int total = n * ACTIONS;         // 1,048,576

    float* partial    = (float*)d_ws;                 // 128 * 128 floats
    float* scaleshift = (float*)d_ws + 128 * 128;     // 128 floats

    const int STATS_BLOCKS = 128;
    bn_stats_kernel<<<STATS_BLOCKS, 256, 0, stream>>>((const f32x4*)x, partial, total / 4);
    bn_finalize_kernel<<<1, 64, 0, stream>>>(partial, bn_w, bn_b, scaleshift,
                                             STATS_BLOCKS, 1.0f / (float)n);

    const int blocks = total / 256;   // 4096 blocks, one per 256 pairs
    spline_main_kernel<<<blocks, 256, 0, stream>>>(x, emb, scaleshift, out);
}

// Round 4
// 62.915 us; speedup vs baseline: 1.1150x; 1.0158x over previous
//
#include <hip/hip_runtime.h>
#include <hip/hip_bf16.h>

#define ACTIONS 64
#define EMB 32
#define DELTA 16
#define EPS 1e-5f

typedef float f32x4 __attribute__((ext_vector_type(4)));

// tanh(x) = 1 - 2/(1+exp(2x)); saturates correctly at +-1.
__device__ __forceinline__ float fast_tanhf(float x) {
    float e = __expf(2.0f * x);
    float r = __builtin_amdgcn_rcpf(1.0f + e);
    return 1.0f - 2.0f * r;
}

// ---------------- Kernel 1: per-column partial sums (float4) ----------------
__global__ void __launch_bounds__(256) bn_stats_kernel(const f32x4* __restrict__ x4,
                                                       float* __restrict__ partial,
                                                       int total4 /* n*64/4 */) {
    const int tid = threadIdx.x;
    f32x4 s = {0.f, 0.f, 0.f, 0.f};
    f32x4 q = {0.f, 0.f, 0.f, 0.f};
    const int stride = gridDim.x * 256;
    for (int i = blockIdx.x * 256 + tid; i < total4; i += stride) {
        f32x4 v = x4[i];
        s += v;
        q += v * v;
    }
    __shared__ f32x4 ssum[256];
    __shared__ f32x4 ssq[256];
    ssum[tid] = s;
    ssq[tid] = q;
    __syncthreads();
    if (tid < 16) {
        f32x4 a = ssum[tid];
        f32x4 b = ssq[tid];
        #pragma unroll
        for (int k = 1; k < 16; ++k) {
            a += ssum[tid + 16 * k];
            b += ssq[tid + 16 * k];
        }
        float* ps = partial + blockIdx.x * 128;
        #pragma unroll
        for (int j = 0; j < 4; ++j) {
            ps[4 * tid + j]      = a[j];
            ps[64 + 4 * tid + j] = b[j];
        }
    }
}

// ---------------- Kernel 2: fold partials -> scale/shift ----------------
__global__ void __launch_bounds__(64) bn_finalize_kernel(const float* __restrict__ partial,
                                                         const float* __restrict__ w,
                                                         const float* __restrict__ b,
                                                         float* __restrict__ scaleshift,
                                                         int nblocks, float inv_n) {
    const int c = threadIdx.x;  // 0..63
    float s = 0.0f, sq = 0.0f;
    for (int i = 0; i < nblocks; ++i) {
        s  += partial[i * 128 + c];
        sq += partial[i * 128 + 64 + c];
    }
    float mean = s * inv_n;
    float var  = fmaxf(sq * inv_n - mean * mean, 0.0f);
    float scale = rsqrtf(var + EPS) * w[c];
    scaleshift[c]      = scale;
    scaleshift[64 + c] = b[c] - mean * scale;
}

// ---------------- Kernel 3: main spline-embedding, LDS-staged table --------
// Block owns 8 columns (colgrp) x rows_per_tile rows. Sub-table (33 knots x
// 8 cols x 32 floats = 33 KiB) staged to LDS once; main loop: no global
// reads except x (32 B/wave/iter), gathers from LDS (each 8-lane group reads
// a contiguous 128-B sub-row -> all 32 banks exactly once, conflict-free),
// pure contiguous 1-KiB/wave nontemporal stores.
// LDS 33792 B -> 4 blocks/CU (16 waves/CU); grid 1024 blocks = 4/CU exactly.
__global__ void __launch_bounds__(256) spline_lds_kernel(const float* __restrict__ x,
                                                         const f32x4* __restrict__ emb4,
                                                         const float* __restrict__ scaleshift,
                                                         f32x4* __restrict__ out4,
                                                         int rows_per_tile) {
    __shared__ f32x4 tab4[33 * 8 * 8];   // [knot k][ci][e4]
    const int tid     = threadIdx.x;
    const int colgrp  = blockIdx.x & 7;
    const int rowtile = blockIdx.x >> 3;
    const int c0      = colgrp * 8;

    // Stage sub-table: f4 index u = k*64 + ci*8 + e4; global row = k*64+c0+ci.
    // Consecutive u -> contiguous global bytes (1 KiB per wave). One-time.
    for (int u = tid; u < 33 * 64; u += 256) {
        const int k    = u >> 6;
        const int rest = u & 63;                 // ci*8 + e4
        tab4[u] = emb4[k * 512 + c0 * 8 + rest];
    }

    const int ci  = (tid >> 3) & 7;   // column within group
    const int e4  = tid & 7;          // which float4 of the 32-float emb row
    const int col = c0 + ci;
    const float scale = scaleshift[col];
    const float shift = scaleshift[64 + col];
    __syncthreads();

    const int row_off = tid >> 6;     // 0..3: each wave owns one x-row per iter
    const int r_end   = (rowtile + 1) * rows_per_tile;

    #pragma unroll 2
    for (int r0 = rowtile * rows_per_tile; r0 < r_end; r0 += 4) {
        const int row = r0 + row_off;
        const float xv = x[row * ACTIONS + col];

        float t = fast_tanhf(fmaf(xv, scale, shift));
        t = fminf(fmaxf(t, -1.0f + 1e-5f), 1.0f - 1e-5f);

        const float td  = t * (float)DELTA;
        const float xlf = floorf(td);
        const float xhf = floorf(td + 1.0f);     // mirror reference
        const int kl = (int)xlf + DELTA;         // 0..31
        const int kh = (int)xhf + DELTA;         // 1..32
        const float wl = xhf - td;               // D*(xh - t)
        const float wh = td - xlf;               // D*(t - xl)

        const f32x4 bl = tab4[(kl * 8 + ci) * 8 + e4];
        const f32x4 bh = tab4[(kh * 8 + ci) * 8 + e4];
        f32x4 o = bh * wh + bl * wl;
        // out f4 index = (row*64+col)*8+e4 = row*512 + c0*8 + ci*8 + e4:
        // contiguous across a wave's 64 lanes -> 1 KiB segment.
        __builtin_nontemporal_store(o, &out4[(row * ACTIONS + col) * 8 + e4]);
    }
}

extern "C" void kernel_launch(void* const* d_in, const int* in_sizes, int n_in,
                              void* d_out, int out_size, void* d_ws, size_t ws_size,
                              hipStream_t stream) {
    const float* x    = (const float*)d_in[0];
    const float* bn_w = (const float*)d_in[1];
    const float* bn_b = (const float*)d_in[2];
    const float* emb  = (const float*)d_in[3];
    float* out        = (float*)d_out;

    const int n = in_sizes[0] / ACTIONS;   // 16384
    const int total = n * ACTIONS;

    float* partial    = (float*)d_ws;                 // 128 * 128 floats
    float* scaleshift = (float*)d_ws + 128 * 128;     // 128 floats

    const int STATS_BLOCKS = 128;
    bn_stats_kernel<<<STATS_BLOCKS, 256, 0, stream>>>((const f32x4*)x, partial, total / 4);
    bn_finalize_kernel<<<1, 64, 0, stream>>>(partial, bn_w, bn_b, scaleshift,
                                             STATS_BLOCKS, 1.0f / (float)n);

    // 8 col-groups x 128 row-tiles = 1024 blocks (4/CU, LDS-limited occupancy)
    const int ROWTILES = 128;
    const int rows_per_tile = n / ROWTILES;   // 128
    spline_lds_kernel<<<8 * ROWTILES, 256, 0, stream>>>(x, (const f32x4*)emb,
                                                        scaleshift, (f32x4*)out,
                                                        rows_per_tile);
}